// Round 8
// baseline (88.952 us; speedup 1.0000x reference)
//
#include <hip/hip_runtime.h>
#include <hip/hip_bf16.h>

// BlockAttention: paged KV-cache prefill attention, block-causal mask.
// B=4, LQ=512, HQ=16, HKV=8, D=128, CTX=2048, LK=2560.
// R1: XCD-aware block index + register prefetch.
// R2: swizzled K/V LDS, double-buffer, one barrier/tile.
// R3: swapped QK^T -> in-register softmax; zero-shuffle PV; defer-max.
// R6: 1024-thread block (16 waves = 4/SIMD), 8 (q,head) groups x 2 kv-halves.
// R7: (a) conflict-free-by-construction staging writes: K row x 32-u32
//     mapping (32 lanes -> 32 banks exactly, b64 writes); V group-disjoint
//     bank residues (bank = 4*swz + g). Read-side layout unchanged.
//     (b) tail balance: block = qb-pair {p, 15-p} (34+40 = 36+38 tiles);
//     all blocks run NT_MAX=40 uniform staging steps, compute gated per wave.

#define B_    4
#define LQ_   512
#define HQ_   16
#define HKV_  8
#define D_    128
#define BLKSZ_ 256
#define BPS_  8
#define CTX_  2048
#define DIFFB_ 128
#define KT_   64
#define NTMAX_ 40
#define SCALE_ 0.08838834764831845f

typedef __attribute__((ext_vector_type(4))) float f32x4;
typedef __attribute__((ext_vector_type(8))) short bf16x8;
typedef __attribute__((ext_vector_type(2))) unsigned u32x2;

__device__ __forceinline__ unsigned cvt_pk2(float a, float b) {
  union { __hip_bfloat162 h; unsigned u; } x;
  x.h = __float22bfloat162_rn(float2{a, b});
  return x.u;
}
union bf8u { bf16x8 v; unsigned u[4]; };

// ---- K tile swizzle (units: shorts), 16B-chunk XOR ----
__device__ __forceinline__ int kidx(int kv, int d) {
  return kv * 128 + ((((d >> 3) ^ kv) & 15) << 3) + (d & 7);
}
// ---- V^T tile swizzle; p is the PHYSICAL (k-label) kv slot ----
__device__ __forceinline__ int vidx(int d, int p) {
  return d * 64 + ((((p >> 3) ^ d ^ (d >> 3)) & 7) << 3) + (p & 7);
}
// kv -> phys k-label within a 32-half: [4][3:2][1:0] -> [3:2][4][1:0]
__device__ __forceinline__ int pk32(int w) {
  return (((w >> 2) & 3) << 3) | (((w >> 4) & 1) << 2) | (w & 3);
}

__global__ __launch_bounds__(1024)
void block_attn_kernel(const float* __restrict__ qg,
                       const float* __restrict__ kcur,
                       const float* __restrict__ vcur,
                       const float* __restrict__ kcache,
                       const float* __restrict__ vcache,
                       const int*   __restrict__ btab,
                       float*       __restrict__ out) {
  // grid 256: blk = qp*32 + b*8 + hkv (qp high bits -> same (b,hkv) per XCD)
  const int blk  = blockIdx.x;
  const int hkv  = blk & 7;
  const int b    = (blk >> 3) & 3;
  const int qp   = blk >> 5;                    // q-pair index 0..7
  const int tid  = threadIdx.x;
  const int lane = tid & 63;
  const int wave = tid >> 6;                    // 0..15
  const int lo   = lane & 15;
  const int hi   = lane >> 4;
  // waves 0-7: q-tile qp; waves 8-15: q-tile 15-qp (tile counts sum to 74)
  const int qsel = wave >> 3;
  const int qb32 = qsel ? (15 - qp) : qp;       // 32-row q tile, 0..15
  const int g2l  = (wave >> 1) & 3;             // group within q-tile
  const int kvh  = wave & 1;                    // kv half 0..1
  const int g2   = wave >> 1;                   // merge-scratch slot 0..7
  const int hq   = hkv * 2 + (g2l >> 1);
  const int qrow0 = qb32 * 32 + (g2l & 1) * 16; // wave's 16 q rows
  const int ntw  = 34 + 2 * (qb32 >> 2);        // this wave's tile count

  // K buffers @0,16384; V buffers @32768,49152 (bytes). Merge scratch
  // Os (128 row-heads x 128 f32 = 64KB) overlays everything after loop.
  __shared__ __align__(16) char smem_raw[65536];
  __shared__ float ms[8][16], ls[8][16];
  float* Os = (float*)smem_raw;

  // ---- Q fragment (scaled bf16): B-frag col=lo(q), k=hi*8+j ----
  bf16x8 qf[4];
  {
    const float* qr = qg + ((size_t)((b * LQ_ + qrow0 + lo)) * HQ_ + hq) * D_;
#pragma unroll
    for (int db = 0; db < 4; ++db) {
      const int d0 = db * 32 + hi * 8;
      f32x4 a = *(const f32x4*)(qr + d0);
      f32x4 c4 = *(const f32x4*)(qr + d0 + 4);
      bf8u f;
      f.u[0] = cvt_pk2(a[0] * SCALE_, a[1] * SCALE_);
      f.u[1] = cvt_pk2(a[2] * SCALE_, a[3] * SCALE_);
      f.u[2] = cvt_pk2(c4[0] * SCALE_, c4[1] * SCALE_);
      f.u[3] = cvt_pk2(c4[2] * SCALE_, c4[3] * SCALE_);
      qf[db] = f.v;
    }
  }

  f32x4 oacc[8];
#pragma unroll
  for (int i = 0; i < 8; ++i) oacc[i] = (f32x4){0.f, 0.f, 0.f, 0.f};
  float mrow = -1e30f, lrow = 0.f;   // per-lane: ONE q-row, 32-kv half

  // ---- staging mappings (conflict-free by construction) ----
  // K: slot i in {0,1}: row = 2*wave + (lane>>5) + 32*i, u32-pair col = lane&31.
  //    Write = one b64; 32 lanes cover 32 banks exactly.
  // V: group gq = lane>>4 selects bank residue (prlow == gq); wave bits give
  //    row-pair and d-half; 16 lanes x 16B contiguous global loads.
  const int l31  = lane & 31;
  const int rK0  = 2 * wave + (lane >> 5);        // K row base (+32 for slot 1)
  const int gq   = lane >> 4;
  const int ev   = lane & 15;
  const int vr0  = 32 * (wave >> 3) + 16 * (gq >> 1) + 4 * (wave & 3) + 2 * (gq & 1);
  const int vD0  = 64 * ((wave >> 2) & 1) + 4 * ev; // V d base (4 cols)
  const int vpr  = (vr0 & 32) + pk32(vr0 & 31);     // physical slot (even)
  f32x4 kreg[2], vreg[2];

  auto issue_loads = [&](int t) {
    const int kbase = t * KT_;          // tile never straddles CTX
    const float *kb_, *vb_;
    if (kbase < CTX_) {
      const int pb = btab[b * BPS_ + (kbase >> 8)];
      const int ro = kbase & 255;
      const size_t base = ((size_t)(pb * BLKSZ_ + ro) * HKV_ + hkv) * D_;
      kb_ = kcache + base;
      vb_ = vcache + base;
    } else {
      const int cur = kbase - CTX_;
      const size_t base = ((size_t)(b * LQ_ + cur) * HKV_ + hkv) * D_;
      kb_ = kcur + base;
      vb_ = vcur + base;
    }
    const size_t rs = (size_t)HKV_ * D_;          // row stride in floats
    kreg[0] = *(const f32x4*)(kb_ + (size_t)rK0 * rs + 4 * l31);
    kreg[1] = *(const f32x4*)(kb_ + (size_t)(rK0 + 32) * rs + 4 * l31);
    vreg[0] = *(const f32x4*)(vb_ + (size_t)vr0 * rs + vD0);
    vreg[1] = *(const f32x4*)(vb_ + (size_t)(vr0 + 1) * rs + vD0);
  };

  auto write_lds = [&](int bsel) {
    short* Kb = (short*)(smem_raw + bsel * 16384);
    short* Vb = (short*)(smem_raw + 32768 + bsel * 16384);
#pragma unroll
    for (int i = 0; i < 2; ++i) {
      u32x2 w;
      w[0] = cvt_pk2(kreg[i][0], kreg[i][1]);
      w[1] = cvt_pk2(kreg[i][2], kreg[i][3]);
      *(u32x2*)&Kb[kidx(rK0 + 32 * i, 4 * l31)] = w;   // 8B-aligned b64
    }
#pragma unroll
    for (int j = 0; j < 4; ++j)
      *(unsigned*)&Vb[vidx(vD0 + j, vpr)] = cvt_pk2(vreg[0][j], vreg[1][j]);
  };

  issue_loads(0);
  write_lds(0);
  __syncthreads();

  for (int t = 0; t < NTMAX_; ++t) {
    const int bsel = t & 1;
    const short* Kb = (const short*)(smem_raw + bsel * 16384);
    const short* Vb = (const short*)(smem_raw + 32768 + bsel * 16384);
    if (t + 1 < NTMAX_) issue_loads(t + 1);

    if (t < ntw) {   // wave-uniform compute gate (tail-balanced)
      // ---- S^T = K Q^T on this wave's 32-kv half: 8 reads, 8 MFMAs ----
      f32x4 sacc[2];
      sacc[0] = (f32x4){0.f, 0.f, 0.f, 0.f};
      sacc[1] = (f32x4){0.f, 0.f, 0.f, 0.f};
#pragma unroll
      for (int cs = 0; cs < 2; ++cs)
#pragma unroll
        for (int db = 0; db < 4; ++db) {
          bf16x8 kf = *(const bf16x8*)&Kb[kidx(kvh * 32 + cs * 16 + lo,
                                               db * 32 + hi * 8)];
          sacc[cs] = __builtin_amdgcn_mfma_f32_16x16x32_bf16(kf, qf[db], sacc[cs], 0, 0, 0);
        }

      // ---- in-register online softmax (one q-row per lane, 32 kv) ----
      float mx;
      {
        float m0 = fmaxf(fmaxf(sacc[0][0], sacc[0][1]), fmaxf(sacc[0][2], sacc[0][3]));
        float m1 = fmaxf(fmaxf(sacc[1][0], sacc[1][1]), fmaxf(sacc[1][2], sacc[1][3]));
        mx = fmaxf(m0, m1);
        mx = fmaxf(mx, __shfl_xor(mx, 16));
        mx = fmaxf(mx, __shfl_xor(mx, 32));
      }
      const bool keep = __all(mx - mrow <= 8.0f);   // defer-max (T13)
      const float mnew = keep ? mrow : fmaxf(mrow, mx);
      float rs = 0.f;
#pragma unroll
      for (int cs = 0; cs < 2; ++cs)
#pragma unroll
        for (int i = 0; i < 4; ++i) {
          const float pv = __expf(sacc[cs][i] - mnew);
          sacc[cs][i] = pv;
          rs += pv;
        }
      rs += __shfl_xor(rs, 16);
      rs += __shfl_xor(rs, 32);
      if (keep) {
        lrow += rs;
      } else {
        const float sc = __expf(mrow - mnew);
        lrow = lrow * sc + rs;
        mrow = mnew;
#pragma unroll
        for (int dt = 0; dt < 8; ++dt) oacc[dt] *= sc;
      }

      // ---- pack P in-lane: k-label = pk32(kv_local) ----
      bf16x8 pa;
      {
        bf8u pk;
        pk.u[0] = cvt_pk2(sacc[0][0], sacc[0][1]);
        pk.u[1] = cvt_pk2(sacc[0][2], sacc[0][3]);
        pk.u[2] = cvt_pk2(sacc[1][0], sacc[1][1]);
        pk.u[3] = cvt_pk2(sacc[1][2], sacc[1][3]);
        pa = pk.v;
      }

      // ---- O^T += V^T P^T : 8 reads, 8 MFMAs ----
#pragma unroll
      for (int dt = 0; dt < 8; ++dt) {
        bf16x8 vf = *(const bf16x8*)&Vb[vidx(dt * 16 + lo, kvh * 32 + hi * 8)];
        oacc[dt] = __builtin_amdgcn_mfma_f32_16x16x32_bf16(vf, pa, oacc[dt], 0, 0, 0);
      }
    }

    if (t + 1 < NTMAX_) write_lds(bsel ^ 1);
    __syncthreads();
  }

  // ---- merge kv-halves: kvh=1 publishes, kvh=0 combines + stores ----
  if (kvh == 1) {
#pragma unroll
    for (int dt = 0; dt < 8; ++dt)
      *(f32x4*)&Os[(size_t)(g2 * 16 + lo) * 128 + dt * 16 + hi * 4] = oacc[dt];
    if (hi == 0) { ms[g2][lo] = mrow; ls[g2][lo] = lrow; }
  }
  __syncthreads();
  if (kvh == 0) {
    const float m1 = ms[g2][lo], l1 = ls[g2][lo];
    const float mstar = fmaxf(mrow, m1);
    const float a0 = __expf(mrow - mstar);
    const float a1 = __expf(m1 - mstar);
    const float linv = 1.f / (lrow * a0 + l1 * a1);
    float* orow = out + ((size_t)(b * LQ_ + qrow0 + lo) * HQ_ + hq) * D_;
#pragma unroll
    for (int dt = 0; dt < 8; ++dt) {
      f32x4 o1 = *(const f32x4*)&Os[(size_t)(g2 * 16 + lo) * 128 + dt * 16 + hi * 4];
      f32x4 o = (oacc[dt] * a0 + o1 * a1) * linv;
      *(f32x4*)(orow + dt * 16 + hi * 4) = o;
    }
  }
}

extern "C" void kernel_launch(void* const* d_in, const int* in_sizes, int n_in,
                              void* d_out, int out_size, void* d_ws, size_t ws_size,
                              hipStream_t stream) {
  (void)in_sizes; (void)n_in; (void)out_size; (void)d_ws; (void)ws_size;
  const float* q      = (const float*)d_in[0];
  const float* k      = (const float*)d_in[1];
  const float* v      = (const float*)d_in[2];
  const float* kcache = (const float*)d_in[3];
  const float* vcache = (const float*)d_in[4];
  const int*   btab   = (const int*)d_in[5];
  float* out = (float*)d_out;

  block_attn_kernel<<<dim3(B_ * HKV_ * (LQ_ / 64)), dim3(1024), 0, stream>>>(
      q, k, v, kcache, vcache, btab, out);
}

// Round 10
// 73.858 us; speedup vs baseline: 1.2044x; 1.2044x over previous
//
#include <hip/hip_runtime.h>
#include <hip/hip_bf16.h>

// BlockAttention: paged KV-cache prefill attention, block-causal mask.
// B=4, LQ=512, HQ=16, HKV=8, D=128, CTX=2048, LK=2560.
// R1: XCD-aware block index. R2: swizzled K/V LDS, dbuf, 1 barrier/tile.
// R3: swapped QK^T, in-register softmax, zero-shuffle PV, defer-max.
// R6: 16 waves @ 16q x kv-half (4/SIMD). R7 (reverted): pairing spilled.
// R8: PRODUCER/CONSUMER split. 512 thr = 4 C-waves (32q x 64kv, every
//     kf/vf fragment feeds 2 q-subtiles -> DS reads halved) + 4 P-waves
//     (global->cvt->LDS, prefetch in flight across raw s_barrier).
// R9: fix R8 correctness bug: V physical slot must be pkmap(r0v) (full
//     6-bit involution, matching the consumer's full-64 k-labels), not
//     (r0v&32)+pkmap(r0v&31) which aliased slots mod 64.

#define B_    4
#define LQ_   512
#define HQ_   16
#define HKV_  8
#define D_    128
#define BLKSZ_ 256
#define BPS_  8
#define CTX_  2048
#define DIFFB_ 128
#define KT_   64
#define SCALE_ 0.08838834764831845f

typedef __attribute__((ext_vector_type(4))) float f32x4;
typedef __attribute__((ext_vector_type(8))) short bf16x8;
typedef __attribute__((ext_vector_type(2))) unsigned u32x2;

__device__ __forceinline__ unsigned cvt_pk2(float a, float b) {
  union { __hip_bfloat162 h; unsigned u; } x;
  x.h = __float22bfloat162_rn(float2{a, b});
  return x.u;
}
union bf8u { bf16x8 v; unsigned u[4]; };

// ---- K tile swizzle (units: shorts), 16B-chunk XOR ----
__device__ __forceinline__ int kidx(int kv, int d) {
  return kv * 128 + ((((d >> 3) ^ kv) & 15) << 3) + (d & 7);
}
// ---- V^T tile swizzle; p is the PHYSICAL (k-label) kv slot ----
__device__ __forceinline__ int vidx(int d, int p) {
  return d * 64 + ((((p >> 3) ^ d ^ (d >> 3)) & 7) << 3) + (p & 7);
}
// kv bit-permute: swap bits[5:4] <-> bits[3:2] (involution, keeps [1:0])
__device__ __forceinline__ int pkmap(int kv) {
  return ((kv & 12) << 2) | ((kv & 48) >> 2) | (kv & 3);
}

__global__ __launch_bounds__(512, 2)
void block_attn_kernel(const float* __restrict__ qg,
                       const float* __restrict__ kcur,
                       const float* __restrict__ vcur,
                       const float* __restrict__ kcache,
                       const float* __restrict__ vcache,
                       const int*   __restrict__ btab,
                       float*       __restrict__ out) {
  // grid 256: blk = qb*32 + b*8 + hkv (qb high bits -> same (b,hkv) per XCD)
  const int blk  = blockIdx.x;
  const int hkv  = blk & 7;
  const int b    = (blk >> 3) & 3;
  const int qb   = blk >> 5;                    // 64-row q tile, 0..7
  const int tid  = threadIdx.x;
  const int lane = tid & 63;
  const int wave = tid >> 6;                    // 0..7
  const int lo   = lane & 15;
  const int hi   = lane >> 4;
  const int nt   = (CTX_ + (qb / 2 + 1) * DIFFB_) / KT_;

  __shared__ __align__(16) short Kl[2][KT_ * D_];   // 2 x 16 KiB, swizzled
  __shared__ __align__(16) short Vl[2][D_ * KT_];   // 2 x 16 KiB, V^T perm+swz

  if (wave < 4) {
    // ================= CONSUMER: 32 q-rows x 64 kv, no global loads ====
    const int hq    = hkv * 2 + (wave >> 1);
    const int qrow0 = qb * 64 + (wave & 1) * 32;

    // Q fragments for both 16-row subtiles (scaled bf16)
    bf16x8 qf[2][4];
#pragma unroll
    for (int sub = 0; sub < 2; ++sub) {
      const float* qr = qg + ((size_t)((b * LQ_ + qrow0 + sub * 16 + lo)) * HQ_ + hq) * D_;
#pragma unroll
      for (int db = 0; db < 4; ++db) {
        const int d0 = db * 32 + hi * 8;
        f32x4 a  = *(const f32x4*)(qr + d0);
        f32x4 c4 = *(const f32x4*)(qr + d0 + 4);
        bf8u f;
        f.u[0] = cvt_pk2(a[0] * SCALE_, a[1] * SCALE_);
        f.u[1] = cvt_pk2(a[2] * SCALE_, a[3] * SCALE_);
        f.u[2] = cvt_pk2(c4[0] * SCALE_, c4[1] * SCALE_);
        f.u[3] = cvt_pk2(c4[2] * SCALE_, c4[3] * SCALE_);
        qf[sub][db] = f.v;
      }
    }

    f32x4 oacc[2][8];
#pragma unroll
    for (int s = 0; s < 2; ++s)
#pragma unroll
      for (int i = 0; i < 8; ++i) oacc[s][i] = (f32x4){0.f, 0.f, 0.f, 0.f};
    float mrow[2] = {-1e30f, -1e30f}, lrow[2] = {0.f, 0.f};

    __syncthreads();   // prologue staging done

    for (int t = 0; t < nt; ++t) {
      const short* Kb = Kl[t & 1];
      const short* Vb = Vl[t & 1];

      // ---- S^T = K Q^T : each kf feeds BOTH subtiles ----
      f32x4 sacc[2][4];
#pragma unroll
      for (int s = 0; s < 2; ++s)
#pragma unroll
        for (int cs = 0; cs < 4; ++cs) sacc[s][cs] = (f32x4){0.f, 0.f, 0.f, 0.f};
#pragma unroll
      for (int cs = 0; cs < 4; ++cs) {
#pragma unroll
        for (int db = 0; db < 4; ++db) {
          bf16x8 kf = *(const bf16x8*)&Kb[kidx(cs * 16 + lo, db * 32 + hi * 8)];
          sacc[0][cs] = __builtin_amdgcn_mfma_f32_16x16x32_bf16(kf, qf[0][db], sacc[0][cs], 0, 0, 0);
          sacc[1][cs] = __builtin_amdgcn_mfma_f32_16x16x32_bf16(kf, qf[1][db], sacc[1][cs], 0, 0, 0);
        }
      }

      // ---- in-register online softmax + pa pack, per subtile ----
      bf16x8 pa[2][2];
#pragma unroll
      for (int sub = 0; sub < 2; ++sub) {
        float m0 = fmaxf(fmaxf(sacc[sub][0][0], sacc[sub][0][1]),
                         fmaxf(sacc[sub][0][2], sacc[sub][0][3]));
        float m1 = fmaxf(fmaxf(sacc[sub][1][0], sacc[sub][1][1]),
                         fmaxf(sacc[sub][1][2], sacc[sub][1][3]));
        float m2 = fmaxf(fmaxf(sacc[sub][2][0], sacc[sub][2][1]),
                         fmaxf(sacc[sub][2][2], sacc[sub][2][3]));
        float m3 = fmaxf(fmaxf(sacc[sub][3][0], sacc[sub][3][1]),
                         fmaxf(sacc[sub][3][2], sacc[sub][3][3]));
        float mx = fmaxf(fmaxf(m0, m1), fmaxf(m2, m3));
        mx = fmaxf(mx, __shfl_xor(mx, 16));
        mx = fmaxf(mx, __shfl_xor(mx, 32));
        const bool keep = __all(mx - mrow[sub] <= 8.0f);   // defer-max
        const float mnew = keep ? mrow[sub] : fmaxf(mrow[sub], mx);
        float rs = 0.f;
#pragma unroll
        for (int cs = 0; cs < 4; ++cs)
#pragma unroll
          for (int i = 0; i < 4; ++i) {
            const float p = __expf(sacc[sub][cs][i] - mnew);
            sacc[sub][cs][i] = p;
            rs += p;
          }
        rs += __shfl_xor(rs, 16);
        rs += __shfl_xor(rs, 32);
        if (keep) {
          lrow[sub] += rs;
        } else {
          const float sc = __expf(mrow[sub] - mnew);
          lrow[sub] = lrow[sub] * sc + rs;
          mrow[sub] = mnew;
#pragma unroll
          for (int dt = 0; dt < 8; ++dt) oacc[sub][dt] *= sc;
        }
#pragma unroll
        for (int ch = 0; ch < 2; ++ch) {
          bf8u p;
          p.u[0] = cvt_pk2(sacc[sub][2 * ch][0],     sacc[sub][2 * ch][1]);
          p.u[1] = cvt_pk2(sacc[sub][2 * ch][2],     sacc[sub][2 * ch][3]);
          p.u[2] = cvt_pk2(sacc[sub][2 * ch + 1][0], sacc[sub][2 * ch + 1][1]);
          p.u[3] = cvt_pk2(sacc[sub][2 * ch + 1][2], sacc[sub][2 * ch + 1][3]);
          pa[sub][ch] = p.v;
        }
      }

      // ---- O^T += V^T P^T : each vf feeds BOTH subtiles ----
#pragma unroll
      for (int ch = 0; ch < 2; ++ch) {
#pragma unroll
        for (int dt = 0; dt < 8; ++dt) {
          bf16x8 vf = *(const bf16x8*)&Vb[vidx(dt * 16 + lo, hi * 16 + ch * 8)];
          oacc[0][dt] = __builtin_amdgcn_mfma_f32_16x16x32_bf16(vf, pa[0][ch], oacc[0][dt], 0, 0, 0);
          oacc[1][dt] = __builtin_amdgcn_mfma_f32_16x16x32_bf16(vf, pa[1][ch], oacc[1][dt], 0, 0, 0);
        }
      }

      __syncthreads();   // C: no VMEM in flight; drains lgkm only
    }

    // ---- epilogue: direct store (no kv-split merge) ----
#pragma unroll
    for (int sub = 0; sub < 2; ++sub) {
      const float inv = 1.f / lrow[sub];
      float* orow = out + ((size_t)(b * LQ_ + qrow0 + sub * 16 + lo) * HQ_ + hq) * D_;
#pragma unroll
      for (int dt = 0; dt < 8; ++dt) {
        f32x4 o4 = oacc[sub][dt] * inv;
        *(f32x4*)(orow + dt * 16 + hi * 4) = o4;
      }
    }
  } else {
    // ================= PRODUCER: stage global -> bf16 -> LDS ==========
    const int pid = tid & 255;           // 0..255
    const int cK  = pid >> 4;            // K row base (+16*i), i=0..3
    const int e   = pid & 15;            // K d-chunk (8 floats at e*8)
    const int qd  = pid >> 4;            // V row-quad 0..15
    const int dc  = pid & 15;            // V d-chunk (8 floats at dc*8)
    const int r0v = qd * 4;
    const int d0v = dc * 8;
    const int P0v = pkmap(r0v);          // FIX: full 6-bit involution ->
                                         // rows r0v..r0v+3 at P0v..P0v+3
    f32x4 kreg[4][2], vreg[4][2];

    auto issue_loads = [&](int t) {
      const int kbase = t * KT_;         // tile never straddles CTX
      const float *kb_, *vb_;
      if (kbase < CTX_) {
        const int pb = btab[b * BPS_ + (kbase >> 8)];
        const size_t base = ((size_t)(pb * BLKSZ_ + (kbase & 255)) * HKV_ + hkv) * D_;
        kb_ = kcache + base; vb_ = vcache + base;
      } else {
        const size_t base = ((size_t)(b * LQ_ + (kbase - CTX_)) * HKV_ + hkv) * D_;
        kb_ = kcur + base;  vb_ = vcur + base;
      }
      const size_t rs = (size_t)HKV_ * D_;
#pragma unroll
      for (int i = 0; i < 4; ++i) {
        const float* kr = kb_ + (size_t)(cK + 16 * i) * rs + e * 8;
        kreg[i][0] = *(const f32x4*)(kr);
        kreg[i][1] = *(const f32x4*)(kr + 4);
      }
#pragma unroll
      for (int m = 0; m < 4; ++m) {
        const float* vr = vb_ + (size_t)(r0v + m) * rs + d0v;
        vreg[m][0] = *(const f32x4*)(vr);
        vreg[m][1] = *(const f32x4*)(vr + 4);
      }
    };

    auto write_lds = [&](int bsel) {
      short* Kb = Kl[bsel];
      short* Vb = Vl[bsel];
#pragma unroll
      for (int i = 0; i < 4; ++i) {      // one b128 per K row-chunk
        bf8u f;
        f.u[0] = cvt_pk2(kreg[i][0][0], kreg[i][0][1]);
        f.u[1] = cvt_pk2(kreg[i][0][2], kreg[i][0][3]);
        f.u[2] = cvt_pk2(kreg[i][1][0], kreg[i][1][1]);
        f.u[3] = cvt_pk2(kreg[i][1][2], kreg[i][1][3]);
        *(bf16x8*)&Kb[kidx(cK + 16 * i, e * 8)] = f.v;
      }
#pragma unroll
      for (int j = 0; j < 8; ++j) {      // one b64 per d: 4 quad-rows packed
        u32x2 w;
        w[0] = cvt_pk2(vreg[0][j >> 2][j & 3], vreg[1][j >> 2][j & 3]);
        w[1] = cvt_pk2(vreg[2][j >> 2][j & 3], vreg[3][j >> 2][j & 3]);
        *(u32x2*)&Vb[vidx(d0v + j, P0v)] = w;
      }
    };

    issue_loads(0);
    write_lds(0);
    if (nt > 1) issue_loads(1);
    asm volatile("s_waitcnt lgkmcnt(0)" ::: "memory");
    __builtin_amdgcn_s_barrier();

    for (int t = 0; t < nt; ++t) {
      if (t + 1 < nt) write_lds((t + 1) & 1);   // auto vmcnt wait on use
      if (t + 2 < nt) issue_loads(t + 2);       // stays in flight across barrier
      asm volatile("s_waitcnt lgkmcnt(0)" ::: "memory");
      __builtin_amdgcn_s_barrier();
    }
  }
}

extern "C" void kernel_launch(void* const* d_in, const int* in_sizes, int n_in,
                              void* d_out, int out_size, void* d_ws, size_t ws_size,
                              hipStream_t stream) {
  (void)in_sizes; (void)n_in; (void)out_size; (void)d_ws; (void)ws_size;
  const float* q      = (const float*)d_in[0];
  const float* k      = (const float*)d_in[1];
  const float* v      = (const float*)d_in[2];
  const float* kcache = (const float*)d_in[3];
  const float* vcache = (const float*)d_in[4];
  const int*   btab   = (const int*)d_in[5];
  float* out = (float*)d_out;

  block_attn_kernel<<<dim3(B_ * HKV_ * (LQ_ / 64)), dim3(512), 0, stream>>>(
      q, k, v, kcache, vcache, btab, out);
}